// Round 7
// baseline (49.789 us; speedup 1.0000x reference)
//
#include <hip/hip_runtime.h>
#include <math.h>

#define IMG 256
#define EBASE 736   // uint-slot offset of packed E-pairs in ws

typedef _Float16 half_t;
typedef _Float16 half2_t __attribute__((ext_vector_type(2)));

__device__ __forceinline__ half2_t bc_h2(unsigned int u) {
    union { unsigned int u; half2_t h; } c; c.u = u; return c.h;
}
__device__ __forceinline__ unsigned int bc_u(half2_t h) {
    union { unsigned int u; half2_t h; } c; c.h = h; return c.u;
}

__device__ __forceinline__ float dot2(half2_t a, half2_t b, float c) {
#if __has_builtin(__builtin_amdgcn_fdot2)
    return __builtin_amdgcn_fdot2(a, b, c, false);
#else
    return fmaf((float)a.x, (float)b.x, fmaf((float)a.y, (float)b.y, c));
#endif
}

// ws layout (32-bit slots):
//   [0..728]            F fp32 (F[u][p][j], border corrections)
//   [EBASE..EBASE+199]  Ep pairs: uint half2(E[2jp],E[2jp+1]) at [jp][sy][8]
__global__ __launch_bounds__(1024) void kkan_precompute(
    const float* __restrict__ bw, const float* __restrict__ sw,
    const float* __restrict__ sc, const float* __restrict__ rw,
    float* __restrict__ ws)
{
    __shared__ float sF[729];
    const int tid = threadIdx.x;
    if (tid < 729) {
        const int u = tid / 81, p = (tid / 9) % 9, j = tid % 9;
        float f = 0.f;
        for (int c = 0; c < 16; ++c) {
            const float w = (j < 8) ? sw[(c * 9 + p) * 8 + j] * sc[c * 9 + p]
                                    : bw[c * 9 + p];
            f += rw[c * 9 + u] * w;
        }
        sF[tid] = f;
        ws[tid] = f;
    }
    __syncthreads();
    unsigned int* wse = (unsigned int*)ws + EBASE;
    if (tid < 200) {
        const int jp = tid / 40, rem = tid % 40, sy = rem / 8, sx = rem % 8;
        unsigned int val = 0u;
        if (sx < 5) {
            float e0 = 0.f, e1 = 0.f;
            for (int uy = 0; uy < 3; ++uy) {
                const int py = sy - uy; if (py < 0 || py > 2) continue;
                for (int ux = 0; ux < 3; ++ux) {
                    const int px = sx - ux; if (px < 0 || px > 2) continue;
                    const float* fb = &sF[((uy * 3 + ux) * 9 + (py * 3 + px)) * 9];
                    e0 += fb[2 * jp];
                    if (2 * jp + 1 < 9) e1 += fb[2 * jp + 1];
                }
            }
            val = bc_u(half2_t{(half_t)e0, (half_t)e1});
        }
        wse[tid] = val;
    }
}

// phi for one halo pixel -> 5 pair-plane dword stores (dense, branchless)
// wave-private layout: plane stride 400 dwords, row stride 20
__device__ __forceinline__ void phi_store(unsigned int* s_phi, int pix, float v) {
    const int yy = pix / 20, xx = pix - yy * 20;
    const float sil = v / (1.f + __expf(-v));
    float u0 = (v + 2.2f) * 2.5f;
    u0 = fminf(fmaxf(u0, 0.f), 11.f);
    float c[12];
    #pragma unroll
    for (int m = 0; m < 12; ++m) {
        const float d = fmaxf(u0 - (float)m, 0.f);
        c[m] = d * d * d;
    }
    float ph[8];
    #pragma unroll
    for (int j = 0; j < 8; ++j)
        ph[j] = (c[j] - 4.f * c[j + 1] + 6.f * c[j + 2]
                 - 4.f * c[j + 3] + c[j + 4]) * (1.f / 6.f);
    unsigned int* dst = &s_phi[yy * 20 + xx];
    dst[0 * 400] = bc_u(half2_t{(half_t)ph[0], (half_t)ph[1]});
    dst[1 * 400] = bc_u(half2_t{(half_t)ph[2], (half_t)ph[3]});
    dst[2 * 400] = bc_u(half2_t{(half_t)ph[4], (half_t)ph[5]});
    dst[3 * 400] = bc_u(half2_t{(half_t)ph[6], (half_t)ph[7]});
    dst[4 * 400] = bc_u(half2_t{(half_t)sil,   (half_t)0.f});
}

__device__ __forceinline__ float phi_at(const unsigned int* s_phi, int j, int r, int c) {
    const half2_t h = bc_h2(s_phi[(j >> 1) * 400 + r * 20 + c]);
    return (j & 1) ? (float)h.y : (float)h.x;
}

// 4 independent waves per block, each owns a 16x16 output tile with a
// private 8KB LDS slice. NO __syncthreads anywhere: in-wave lgkmcnt ordering
// covers the phi-write -> conv-read dependence, so waves stream past each
// other and hide each other's LDS/global latency.
__global__ __launch_bounds__(256, 5) void kkan_fused(
    const float* __restrict__ x, const float* __restrict__ ws,
    const float* __restrict__ rb, float* __restrict__ out)
{
    __shared__ __align__(16) unsigned int s_phi_all[4 * 2000];   // 32000 B

    const int tid  = threadIdx.x;
    const int w    = tid >> 6;
    const int lane = tid & 63;
    unsigned int* s_phi = s_phi_all + w * 2000;

    const int gx0 = blockIdx.x * 32 + (w & 1) * 16;
    const int gy0 = blockIdx.y * 32 + (w >> 1) * 16;
    const int b   = blockIdx.z;
    const float* xb = x + (size_t)b * (IMG * IMG);

    // ---- hoisted halo loads (20x20 = 400 px, 7 strides of 64 lanes) ----
    float vx[7];
    #pragma unroll
    for (int it = 0; it < 7; ++it) {
        const int pix = lane + it * 64;
        float v = 0.f;
        if (it < 6 || lane < 16) {
            const int yy = pix / 20, xx = pix - yy * 20;
            const int gy = gy0 - 2 + yy, gx = gx0 - 2 + xx;
            if ((unsigned)gy < (unsigned)IMG && (unsigned)gx < (unsigned)IMG)
                v = xb[gy * IMG + gx];
        }
        vx[it] = v;
    }

    // ---- phi: dense pair-plane writes into the wave-private slice ----
    #pragma unroll
    for (int it = 0; it < 6; ++it) phi_store(s_phi, lane + it * 64, vx[it]);
    if (lane < 16) phi_store(s_phi, lane + 384, vx[6]);

    // ---- 5x5 conv over 5 pair-planes: 4 px/thread, b128 phi reads ----
    const int ly  = lane >> 2;
    const int lx0 = (lane & 3) * 4;
    const unsigned int* Eu = (const unsigned int*)ws + EBASE;

    float aA0 = 0.f, aB0 = 0.f, aA1 = 0.f, aB1 = 0.f;
    float aA2 = 0.f, aB2 = 0.f, aA3 = 0.f, aB3 = 0.f;

    #pragma unroll
    for (int jp = 0; jp < 5; ++jp) {
        #pragma unroll
        for (int sy = 0; sy < 5; ++sy) {
            const unsigned int* eb = &Eu[(jp * 5 + sy) * 8];
            const half2_t e0 = bc_h2(eb[0]);
            const half2_t e1 = bc_h2(eb[1]);
            const half2_t e2 = bc_h2(eb[2]);
            const half2_t e3 = bc_h2(eb[3]);
            const half2_t e4 = bc_h2(eb[4]);
            const unsigned int* prow = &s_phi[jp * 400 + (ly + sy) * 20 + lx0];
            const uint4 pa = *(const uint4*)prow;
            const uint4 pb = *(const uint4*)(prow + 4);
            const half2_t q0 = bc_h2(pa.x), q1 = bc_h2(pa.y);
            const half2_t q2 = bc_h2(pa.z), q3 = bc_h2(pa.w);
            const half2_t q4 = bc_h2(pb.x), q5 = bc_h2(pb.y);
            const half2_t q6 = bc_h2(pb.z), q7 = bc_h2(pb.w);
            aA0 = dot2(q0, e0, dot2(q2, e2, dot2(q4, e4, aA0)));
            aB0 = dot2(q1, e1, dot2(q3, e3, aB0));
            aA1 = dot2(q1, e0, dot2(q3, e2, dot2(q5, e4, aA1)));
            aB1 = dot2(q2, e1, dot2(q4, e3, aB1));
            aA2 = dot2(q2, e0, dot2(q4, e2, dot2(q6, e4, aA2)));
            aB2 = dot2(q3, e1, dot2(q5, e3, aB2));
            aA3 = dot2(q3, e0, dot2(q5, e2, dot2(q7, e4, aA3)));
            aB3 = dot2(q4, e1, dot2(q6, e3, aB3));
        }
    }
    float a0 = aA0 + aB0, a1 = aA1 + aB1, a2 = aA2 + aB2, a3 = aA3 + aB3;

    // ---- border correction (edge pixels only): F from ws (L2) ----
    const int gy  = gy0 + ly;
    const int gxb = gx0 + lx0;
    if (gy < 2 || gy > 253 || gxb < 2 || gxb > 250) {
        #pragma unroll
        for (int i = 0; i < 4; ++i) {
            const int gx = gxb + i;
            float corr = 0.f;
            for (int uy = 0; uy < 3; ++uy) {
                const int qy = gy + uy - 1;
                for (int ux = 0; ux < 3; ++ux) {
                    const int qx = gx + ux - 1;
                    if ((unsigned)qy < (unsigned)IMG && (unsigned)qx < (unsigned)IMG)
                        continue;
                    for (int p = 0; p < 9; ++p) {
                        const int ry = ly + uy + (p / 3);
                        const int rx = lx0 + i + ux + (p % 3);
                        const float* fp = &ws[((uy * 3 + ux) * 9 + p) * 9];
                        for (int jj = 0; jj < 9; ++jj)
                            corr += fp[jj] * phi_at(s_phi, jj, ry, rx);
                    }
                }
            }
            if (i == 0) a0 -= corr;
            else if (i == 1) a1 -= corr;
            else if (i == 2) a2 -= corr;
            else a3 -= corr;
        }
    }

    const float rbv = rb[0];
    float4 o4; o4.x = a0 + rbv; o4.y = a1 + rbv; o4.z = a2 + rbv; o4.w = a3 + rbv;
    *(float4*)&out[(size_t)b * (IMG * IMG) + gy * IMG + gxb] = o4;
}

extern "C" void kernel_launch(void* const* d_in, const int* in_sizes, int n_in,
                              void* d_out, int out_size, void* d_ws, size_t ws_size,
                              hipStream_t stream) {
    const float* x             = (const float*)d_in[0];
    const float* base_w        = (const float*)d_in[1];
    const float* spline_w      = (const float*)d_in[2];
    const float* spline_scaler = (const float*)d_in[3];
    const float* restore_w     = (const float*)d_in[4];
    const float* restore_b     = (const float*)d_in[5];
    float* out = (float*)d_out;
    float* ws  = (float*)d_ws;

    kkan_precompute<<<dim3(1), dim3(1024), 0, stream>>>(
        base_w, spline_w, spline_scaler, restore_w, ws);

    kkan_fused<<<dim3(8, 8, 32), dim3(256), 0, stream>>>(x, ws, restore_b, out);
}

// Round 8
// 47.562 us; speedup vs baseline: 1.0468x; 1.0468x over previous
//
#include <hip/hip_runtime.h>
#include <math.h>

#define IMG 256
#define TS 32
#define EBASE 736   // uint-slot offset of packed E-pairs in ws

typedef _Float16 half_t;
typedef _Float16 half2_t __attribute__((ext_vector_type(2)));

__device__ __forceinline__ half2_t bc_h2(unsigned int u) {
    union { unsigned int u; half2_t h; } c; c.u = u; return c.h;
}
__device__ __forceinline__ unsigned int bc_u(half2_t h) {
    union { unsigned int u; half2_t h; } c; c.h = h; return c.u;
}

__device__ __forceinline__ float dot2(half2_t a, half2_t b, float c) {
#if __has_builtin(__builtin_amdgcn_fdot2)
    return __builtin_amdgcn_fdot2(a, b, c, false);
#else
    return fmaf((float)a.x, (float)b.x, fmaf((float)a.y, (float)b.y, c));
#endif
}

// ws layout (32-bit slots):
//   [0..728]            F fp32 (F[u][p][j], border corrections)
//   [EBASE..EBASE+199]  Ep pairs: uint half2(E[2jp],E[2jp+1]) at [jp][sy][8]
__global__ __launch_bounds__(1024) void kkan_precompute(
    const float* __restrict__ bw, const float* __restrict__ sw,
    const float* __restrict__ sc, const float* __restrict__ rw,
    float* __restrict__ ws)
{
    __shared__ float sF[729];
    const int tid = threadIdx.x;
    if (tid < 729) {
        const int u = tid / 81, p = (tid / 9) % 9, j = tid % 9;
        float f = 0.f;
        for (int c = 0; c < 16; ++c) {
            const float w = (j < 8) ? sw[(c * 9 + p) * 8 + j] * sc[c * 9 + p]
                                    : bw[c * 9 + p];
            f += rw[c * 9 + u] * w;
        }
        sF[tid] = f;
        ws[tid] = f;
    }
    __syncthreads();
    unsigned int* wse = (unsigned int*)ws + EBASE;
    if (tid < 200) {
        const int jp = tid / 40, rem = tid % 40, sy = rem / 8, sx = rem % 8;
        unsigned int val = 0u;
        if (sx < 5) {
            float e0 = 0.f, e1 = 0.f;
            for (int uy = 0; uy < 3; ++uy) {
                const int py = sy - uy; if (py < 0 || py > 2) continue;
                for (int ux = 0; ux < 3; ++ux) {
                    const int px = sx - ux; if (px < 0 || px > 2) continue;
                    const float* fb = &sF[((uy * 3 + ux) * 9 + (py * 3 + px)) * 9];
                    e0 += fb[2 * jp];
                    if (2 * jp + 1 < 9) e1 += fb[2 * jp + 1];
                }
            }
            val = bc_u(half2_t{(half_t)e0, (half_t)e1});
        }
        wse[tid] = val;
    }
}

// phi for one halo pixel -> 5 pair-plane dword stores (dense, branchless)
// block layout: plane stride 1296 dwords, row stride 36
__device__ __forceinline__ void phi_store(unsigned int* s_phi, int pix, float v) {
    const int yy = pix / 36, xx = pix - yy * 36;
    const float sil = v / (1.f + __expf(-v));
    float u0 = (v + 2.2f) * 2.5f;
    u0 = fminf(fmaxf(u0, 0.f), 11.f);
    float c[12];
    #pragma unroll
    for (int m = 0; m < 12; ++m) {
        const float d = fmaxf(u0 - (float)m, 0.f);
        c[m] = d * d * d;
    }
    float ph[8];
    #pragma unroll
    for (int j = 0; j < 8; ++j)
        ph[j] = (c[j] - 4.f * c[j + 1] + 6.f * c[j + 2]
                 - 4.f * c[j + 3] + c[j + 4]) * (1.f / 6.f);
    unsigned int* dst = &s_phi[yy * 36 + xx];
    dst[0 * 1296] = bc_u(half2_t{(half_t)ph[0], (half_t)ph[1]});
    dst[1 * 1296] = bc_u(half2_t{(half_t)ph[2], (half_t)ph[3]});
    dst[2 * 1296] = bc_u(half2_t{(half_t)ph[4], (half_t)ph[5]});
    dst[3 * 1296] = bc_u(half2_t{(half_t)ph[6], (half_t)ph[7]});
    dst[4 * 1296] = bc_u(half2_t{(half_t)sil,   (half_t)0.f});
}

__device__ __forceinline__ float phi_at(const unsigned int* s_phi, int j, int r, int c) {
    const half2_t h = bc_h2(s_phi[(j >> 1) * 1296 + r * 36 + c]);
    return (j & 1) ? (float)h.y : (float)h.x;
}

// one conv row: 8 consecutive pixel pair-values (pa,pb) x 5-tap E row (eb)
__device__ __forceinline__ void conv_row(uint4 pa, uint4 pb, const unsigned int* eb,
    float& aA0, float& aB0, float& aA1, float& aB1,
    float& aA2, float& aB2, float& aA3, float& aB3)
{
    const half2_t e0 = bc_h2(eb[0]), e1 = bc_h2(eb[1]), e2 = bc_h2(eb[2]);
    const half2_t e3 = bc_h2(eb[3]), e4 = bc_h2(eb[4]);
    const half2_t q0 = bc_h2(pa.x), q1 = bc_h2(pa.y);
    const half2_t q2 = bc_h2(pa.z), q3 = bc_h2(pa.w);
    const half2_t q4 = bc_h2(pb.x), q5 = bc_h2(pb.y);
    const half2_t q6 = bc_h2(pb.z), q7 = bc_h2(pb.w);
    aA0 = dot2(q0, e0, dot2(q2, e2, dot2(q4, e4, aA0)));
    aB0 = dot2(q1, e1, dot2(q3, e3, aB0));
    aA1 = dot2(q1, e0, dot2(q3, e2, dot2(q5, e4, aA1)));
    aB1 = dot2(q2, e1, dot2(q4, e3, aB1));
    aA2 = dot2(q2, e0, dot2(q4, e2, dot2(q6, e4, aA2)));
    aB2 = dot2(q3, e1, dot2(q5, e3, aB2));
    aA3 = dot2(q3, e0, dot2(q5, e2, dot2(q7, e4, aA3)));
    aB3 = dot2(q4, e1, dot2(q6, e3, aB3));
}

// load all 5 rows (2 uint4 each) of plane-pair JP into named registers
#define LOAD_JP(P, JP) do {                                                  \
    const unsigned int* rbase_ = s_phi + (JP) * 1296 + ly * 36 + lx0;        \
    P##0a = *(const uint4*)(rbase_ + 0 * 36); P##0b = *(const uint4*)(rbase_ + 0 * 36 + 4); \
    P##1a = *(const uint4*)(rbase_ + 1 * 36); P##1b = *(const uint4*)(rbase_ + 1 * 36 + 4); \
    P##2a = *(const uint4*)(rbase_ + 2 * 36); P##2b = *(const uint4*)(rbase_ + 2 * 36 + 4); \
    P##3a = *(const uint4*)(rbase_ + 3 * 36); P##3b = *(const uint4*)(rbase_ + 3 * 36 + 4); \
    P##4a = *(const uint4*)(rbase_ + 4 * 36); P##4b = *(const uint4*)(rbase_ + 4 * 36 + 4); \
} while (0)

#define COMP_JP(P, JP) do {                                                  \
    conv_row(P##0a, P##0b, Eu + ((JP) * 5 + 0) * 8, aA0, aB0, aA1, aB1, aA2, aB2, aA3, aB3); \
    conv_row(P##1a, P##1b, Eu + ((JP) * 5 + 1) * 8, aA0, aB0, aA1, aB1, aA2, aB2, aA3, aB3); \
    conv_row(P##2a, P##2b, Eu + ((JP) * 5 + 2) * 8, aA0, aB0, aA1, aB1, aA2, aB2, aA3, aB3); \
    conv_row(P##3a, P##3b, Eu + ((JP) * 5 + 3) * 8, aA0, aB0, aA1, aB1, aA2, aB2, aA3, aB3); \
    conv_row(P##4a, P##4b, Eu + ((JP) * 5 + 4) * 8, aA0, aB0, aA1, aB1, aA2, aB2, aA3, aB3); \
} while (0)

__global__ __launch_bounds__(256, 4) void kkan_fused(
    const float* __restrict__ x, const float* __restrict__ ws,
    const float* __restrict__ rb, float* __restrict__ out)
{
    __shared__ __align__(16) unsigned int s_phi[5 * 36 * 36];   // 25.9 KB

    const int tid = threadIdx.x;
    const int gx0 = blockIdx.x * TS, gy0 = blockIdx.y * TS, b = blockIdx.z;
    const float* xb = x + (size_t)b * (IMG * IMG);

    // ---- hoisted halo loads (latency overlaps phi arithmetic) ----
    float vx[6];
    #pragma unroll
    for (int it = 0; it < 6; ++it) {
        const int pix = tid + it * 256;
        float v = 0.f;
        if (it < 5 || tid < 16) {
            const int yy = pix / 36, xx = pix - yy * 36;
            const int gy = gy0 - 2 + yy, gx = gx0 - 2 + xx;
            if ((unsigned)gy < (unsigned)IMG && (unsigned)gx < (unsigned)IMG)
                v = xb[gy * IMG + gx];
        }
        vx[it] = v;
    }

    // ---- phi: dense pair-plane writes, no zero-fill needed ----
    #pragma unroll
    for (int it = 0; it < 5; ++it) phi_store(s_phi, tid + it * 256, vx[it]);
    if (tid < 16) phi_store(s_phi, tid + 1280, vx[5]);
    __syncthreads();

    // ---- 5x5 conv, register double-buffered over plane-pairs ----
    const int ly  = tid >> 3;
    const int lx0 = (tid & 7) * 4;
    const unsigned int* Eu = (const unsigned int*)ws + EBASE;

    float aA0 = 0.f, aB0 = 0.f, aA1 = 0.f, aB1 = 0.f;
    float aA2 = 0.f, aB2 = 0.f, aA3 = 0.f, aB3 = 0.f;

    uint4 A0a, A0b, A1a, A1b, A2a, A2b, A3a, A3b, A4a, A4b;
    uint4 B0a, B0b, B1a, B1b, B2a, B2b, B3a, B3b, B4a, B4b;

    LOAD_JP(A, 0);
    LOAD_JP(B, 1); COMP_JP(A, 0);
    LOAD_JP(A, 2); COMP_JP(B, 1);
    LOAD_JP(B, 3); COMP_JP(A, 2);
    LOAD_JP(A, 4); COMP_JP(B, 3);
    COMP_JP(A, 4);

    float a0 = aA0 + aB0, a1 = aA1 + aB1, a2 = aA2 + aB2, a3 = aA3 + aB3;

    // ---- border correction (edge pixels only): F from ws (L2) ----
    const int gy  = gy0 + ly;
    const int gxb = gx0 + lx0;
    if (gy < 2 || gy > 253 || gxb < 2 || gxb > 250) {
        #pragma unroll
        for (int i = 0; i < 4; ++i) {
            const int gx = gxb + i;
            float corr = 0.f;
            for (int uy = 0; uy < 3; ++uy) {
                const int qy = gy + uy - 1;
                for (int ux = 0; ux < 3; ++ux) {
                    const int qx = gx + ux - 1;
                    if ((unsigned)qy < (unsigned)IMG && (unsigned)qx < (unsigned)IMG)
                        continue;
                    for (int p = 0; p < 9; ++p) {
                        const int ry = ly + uy + (p / 3);
                        const int rx = lx0 + i + ux + (p % 3);
                        const float* fp = &ws[((uy * 3 + ux) * 9 + p) * 9];
                        for (int jj = 0; jj < 9; ++jj)
                            corr += fp[jj] * phi_at(s_phi, jj, ry, rx);
                    }
                }
            }
            if (i == 0) a0 -= corr;
            else if (i == 1) a1 -= corr;
            else if (i == 2) a2 -= corr;
            else a3 -= corr;
        }
    }

    const float rbv = rb[0];
    float4 o4; o4.x = a0 + rbv; o4.y = a1 + rbv; o4.z = a2 + rbv; o4.w = a3 + rbv;
    *(float4*)&out[(size_t)b * (IMG * IMG) + gy * IMG + gxb] = o4;
}

extern "C" void kernel_launch(void* const* d_in, const int* in_sizes, int n_in,
                              void* d_out, int out_size, void* d_ws, size_t ws_size,
                              hipStream_t stream) {
    const float* x             = (const float*)d_in[0];
    const float* base_w        = (const float*)d_in[1];
    const float* spline_w      = (const float*)d_in[2];
    const float* spline_scaler = (const float*)d_in[3];
    const float* restore_w     = (const float*)d_in[4];
    const float* restore_b     = (const float*)d_in[5];
    float* out = (float*)d_out;
    float* ws  = (float*)d_ws;

    kkan_precompute<<<dim3(1), dim3(1024), 0, stream>>>(
        base_w, spline_w, spline_scaler, restore_w, ws);

    kkan_fused<<<dim3(8, 8, 32), dim3(256), 0, stream>>>(x, ws, restore_b, out);
}